// Round 8
// baseline (3176.593 us; speedup 1.0000x reference)
//
#include <hip/hip_runtime.h>
#include <cstdint>

typedef unsigned int u32;
typedef unsigned long long u64;

#define BATCH 8
#define H 1024
#define W 1024
#define HW (H*W)
#define NPIX (BATCH*HW)
#define KTOP 2048
#define NBIN 8192
#define KEYCAP 8192
#define CAPP 131072
#define CAPC 65536
#define TARGET 2080

#define D9 1e-3f
#define DV 1e-4f

// ws layout (bytes); [0, OFF_PASS) memset to 0 each launch
#define OFF_MISC 0                          // u32: pass[0..8) chk[8..16) kcnt[16..24) cut[24..32)
#define OFF_HIST 4096                       // u32[8][NBIN] = 256 KB
#define OFF_PASS (OFF_HIST + BATCH*NBIN*4)
#define OFF_CHK  (OFF_PASS + BATCH*CAPP*4)
#define OFF_KEY  (OFF_CHK  + BATCH*CAPC*4)

#define LD4(p) (*reinterpret_cast<const float4*>(p))
#define ST4(p,v) (*reinterpret_cast<float4*>(p) = (v))

// ---------------- f64 dilated conv + relu (IDENTICAL to green rounds 3-7) ----------------
__device__ __forceinline__ double conv_resp_f64(
    const float* __restrict__ in, const float* __restrict__ wc,
    const float* __restrict__ wsw, int b, int y, int x)
{
  const float* base = in + (size_t)b * 3 * HW;
  const float* Sp = base;
  const float* Cp = base + HW;
  double resp = 0.0;
  const int dil[3] = {1, 4, 16};
  #pragma unroll
  for (int di = 0; di < 3; ++di) {
    int d = dil[di];
    double ac = 0.0, as = 0.0;
    #pragma unroll
    for (int ky = 0; ky < 3; ++ky) {
      int yy = y + (ky - 1) * d;
      bool yok = ((unsigned)yy < (unsigned)H);
      #pragma unroll
      for (int kx = 0; kx < 3; ++kx) {
        int xx = x + (kx - 1) * d;
        bool ok = yok && ((unsigned)xx < (unsigned)W);
        double a  = ok ? (double)Cp[yy * W + xx] : 0.0;
        double s2 = ok ? (double)Sp[yy * W + xx] : 0.0;
        ac = fma(a,  (double)wc[di * 9 + ky * 3 + kx], ac);
        as = fma(s2, (double)wsw[di * 9 + ky * 3 + kx], as);
      }
    }
    resp += ac;
    resp += as;
  }
  return resp > 0.0 ? resp : 0.0;
}

__device__ __forceinline__ u64 make_key(double val, int p) {
  u64 dbits = __double_as_longlong(val);
  return (dbits & ~0xFFFFFull) | (u64)((~(u32)p) & 0xFFFFFu);
}

// ---------------- guarded scalar f32 conv (border path) ----------------
__device__ __forceinline__ float conv_f32_guard(
    const float* __restrict__ Sp, const float* __restrict__ Cp,
    const float* __restrict__ wc, const float* __restrict__ wsw, int y, int x)
{
  float resp = 0.f;
  #pragma unroll
  for (int di = 0; di < 3; ++di) {
    const int d = (di == 0) ? 1 : (di == 1) ? 4 : 16;
    float ac = 0.f, as = 0.f;
    #pragma unroll
    for (int ky = 0; ky < 3; ++ky) {
      int yy = y + (ky - 1) * d;
      bool yok = ((unsigned)yy < (unsigned)H);
      #pragma unroll
      for (int kx = 0; kx < 3; ++kx) {
        int xx = x + (kx - 1) * d;
        bool ok = yok && ((unsigned)xx < (unsigned)W);
        float a  = ok ? Cp[yy * W + xx] : 0.f;
        float s2 = ok ? Sp[yy * W + xx] : 0.f;
        ac = fmaf(a,  wc[di * 9 + ky * 3 + kx], ac);
        as = fmaf(s2, wsw[di * 9 + ky * 3 + kx], as);
      }
    }
    resp += ac;
    resp += as;
  }
  return resp;
}

// ---------------- kernel 1: 4 px/thread, f4 loads: outputs + f32 conv ----------------
__global__ __launch_bounds__(256) void conv32_kernel(
    const float* __restrict__ in, const float* __restrict__ wc,
    const float* __restrict__ wsw, float* __restrict__ out0,
    float* __restrict__ convr)
{
  int gid = blockIdx.x * 256 + threadIdx.x;
  int b = gid >> 18;
  int p0 = (gid & ((HW / 4) - 1)) * 4;
  int y = p0 >> 10;
  int x0 = p0 & (W - 1);

  const float* base = in + (size_t)b * 3 * HW;
  const float* Sp = base;
  const float* Cp = base + HW;
  const float* Rp = base + 2 * HW;

  float4 S4 = LD4(Sp + p0);
  float4 C4 = LD4(Cp + p0);
  float4 R4 = LD4(Rp + p0);
  float* ob = out0 + (size_t)b * 3 * HW;
  ST4(ob + p0, S4);
  ST4(ob + HW + p0, C4);
  float4 E4 = make_float4(expf(R4.x) - 1.f, expf(R4.y) - 1.f,
                          expf(R4.z) - 1.f, expf(R4.w) - 1.f);
  ST4(ob + 2 * HW + p0, E4);

  float acc[4] = {0.f, 0.f, 0.f, 0.f};
  bool interior = (x0 >= 16) && (x0 <= 1004) && (y >= 16) && (y <= 1007);
  if (interior) {
    // CONTIG dilations (1,4): window = cols x0-4..x0+7 ; D16: L/M/R blocks
    #define DIL_CONTIG(PTR, WP, DI, D) { \
      _Pragma("unroll") \
      for (int ky = 0; ky < 3; ++ky) { \
        const float* rp = (PTR) + (y + (ky - 1) * (D)) * W; \
        float4 Lq = LD4(rp + x0 - 4); \
        float4 Mq = LD4(rp + x0); \
        float4 Rq = LD4(rp + x0 + 4); \
        float win[12] = {Lq.x,Lq.y,Lq.z,Lq.w, Mq.x,Mq.y,Mq.z,Mq.w, Rq.x,Rq.y,Rq.z,Rq.w}; \
        _Pragma("unroll") \
        for (int kx = 0; kx < 3; ++kx) { \
          float wv = (WP)[(DI) * 9 + ky * 3 + kx]; \
          _Pragma("unroll") \
          for (int i = 0; i < 4; ++i) \
            acc[i] = fmaf(win[i + (kx - 1) * (D) + 4], wv, acc[i]); \
        } \
      } }
    #define DIL16(PTR, WP, DI) { \
      _Pragma("unroll") \
      for (int ky = 0; ky < 3; ++ky) { \
        const float* rp = (PTR) + (y + (ky - 1) * 16) * W; \
        float4 Lq = LD4(rp + x0 - 16); \
        float4 Mq = LD4(rp + x0); \
        float4 Rq = LD4(rp + x0 + 16); \
        float win[12] = {Lq.x,Lq.y,Lq.z,Lq.w, Mq.x,Mq.y,Mq.z,Mq.w, Rq.x,Rq.y,Rq.z,Rq.w}; \
        _Pragma("unroll") \
        for (int kx = 0; kx < 3; ++kx) { \
          float wv = (WP)[(DI) * 9 + ky * 3 + kx]; \
          _Pragma("unroll") \
          for (int i = 0; i < 4; ++i) \
            acc[i] = fmaf(win[kx * 4 + i], wv, acc[i]); \
        } \
      } }
    DIL_CONTIG(Cp, wc, 0, 1)
    DIL_CONTIG(Sp, wsw, 0, 1)
    DIL_CONTIG(Cp, wc, 1, 4)
    DIL_CONTIG(Sp, wsw, 1, 4)
    DIL16(Cp, wc, 2)
    DIL16(Sp, wsw, 2)
  } else {
    #pragma unroll
    for (int i = 0; i < 4; ++i)
      acc[i] = conv_f32_guard(Sp, Cp, wc, wsw, y, x0 + i);
  }
  float4 CV = make_float4(fmaxf(acc[0], 0.f), fmaxf(acc[1], 0.f),
                          fmaxf(acc[2], 0.f), fmaxf(acc[3], 0.f));
  ST4(convr + (size_t)b * HW + p0, CV);
}

// ---------------- kernel 2: 4 px/thread f4 margin screen ----------------
__global__ __launch_bounds__(256) void screen_kernel(
    const float* __restrict__ convr, u32* __restrict__ passlist,
    u32* __restrict__ checklist, u32* __restrict__ hist, u32* __restrict__ misc)
{
  int gid = blockIdx.x * 256 + threadIdx.x;
  int b = gid >> 18;
  int p0 = (gid & ((HW / 4) - 1)) * 4;
  int y = p0 >> 10;
  int x0 = p0 & (W - 1);
  if (y < 5 || y > H - 6) return;
  if (x0 + 3 < 5 || x0 > W - 6) return;

  const float* cr = convr + (size_t)b * HW;
  float r[5][12];
  #pragma unroll
  for (int ry = 0; ry < 5; ++ry) {
    const float* rp = cr + (y + ry - 2) * W + x0;
    float4 A = LD4(rp - 4);
    float4 Bq = LD4(rp);
    float4 Cq = LD4(rp + 4);
    r[ry][0]=A.x; r[ry][1]=A.y; r[ry][2]=A.z; r[ry][3]=A.w;
    r[ry][4]=Bq.x; r[ry][5]=Bq.y; r[ry][6]=Bq.z; r[ry][7]=Bq.w;
    r[ry][8]=Cq.x; r[ry][9]=Cq.y; r[ry][10]=Cq.z; r[ry][11]=Cq.w;
  }

  // vertical 3-sums over cols x0-2..x0+5 (win idx 2..9), same add order as green screen
  float vs0[8], vs1[8], vs2[8];
  #pragma unroll
  for (int c = 0; c < 8; ++c) {
    vs0[c] = r[0][c + 2] + r[1][c + 2] + r[2][c + 2];
    vs1[c] = r[1][c + 2] + r[2][c + 2] + r[3][c + 2];
    vs2[c] = r[2][c + 2] + r[3][c + 2] + r[4][c + 2];
  }
  float hs0[6], hs1[6], hs2[6];
  #pragma unroll
  for (int c = 0; c < 6; ++c) {
    hs0[c] = vs0[c] + vs0[c + 1] + vs0[c + 2];
    hs1[c] = vs1[c] + vs1[c + 1] + vs1[c + 2];
    hs2[c] = vs2[c] + vs2[c + 1] + vs2[c + 2];
  }

  #pragma unroll
  for (int i = 0; i < 4; ++i) {
    int x = x0 + i;
    if (x < 5 || x > W - 6) continue;
    float sc9 = hs1[i + 1];
    float val = r[2][i + 4];
    float m9 = fmaxf(fmaxf(fmaxf(hs0[i], hs0[i + 1]), fmaxf(hs0[i + 2], hs1[i])),
                     fmaxf(fmaxf(hs1[i + 2], hs2[i]), fmaxf(hs2[i + 1], hs2[i + 2])));

    if ((sc9 < 0.9f - D9) || (sc9 < m9 - D9) || (val < 0.1f - DV)) continue;

    int p = p0 + i;
    bool pass = (sc9 > 0.9f + D9) && (sc9 >= m9 + D9) && (val > 0.1f + DV);
    if (pass) {
      u32 pos = atomicAdd(&misc[b], 1u);
      if (pos < CAPP) passlist[(size_t)b * CAPP + pos] = (u32)p;
      atomicAdd(&hist[b * NBIN + (__float_as_uint(val) >> 19)], 1u);
    } else {
      u32 pos = atomicAdd(&misc[8 + b], 1u);
      if (pos < CAPC) checklist[(size_t)b * CAPC + pos] = (u32)p;
    }
  }
}

// ---------------- kernel 3: suffix-scan hist -> f32 cut (rank TARGET, one-bin slack) ------
__global__ __launch_bounds__(1024) void cutscan_kernel(
    const u32* __restrict__ hist, u32* __restrict__ misc)
{
  __shared__ u32 sfx[NBIN];
  int b = blockIdx.x;
  int tid = threadIdx.x;
  const u32* h = hist + b * NBIN;
  #pragma unroll
  for (int k = 0; k < 8; ++k) sfx[tid * 8 + k] = h[tid * 8 + k];
  __syncthreads();

  for (int off = 1; off < NBIN; off <<= 1) {
    u32 t[8];
    #pragma unroll
    for (int k = 0; k < 8; ++k) {
      int i = tid * 8 + k;
      t[k] = (i + off < NBIN) ? sfx[i + off] : 0u;
    }
    __syncthreads();
    #pragma unroll
    for (int k = 0; k < 8; ++k) sfx[tid * 8 + k] += t[k];
    __syncthreads();
  }

  if (sfx[0] < TARGET) return;

  #pragma unroll
  for (int k = 0; k < 8; ++k) {
    int i = tid * 8 + k;
    u32 s = sfx[i];
    u32 nxt = (i + 1 < NBIN) ? sfx[i + 1] : 0u;
    if (s >= TARGET && nxt < TARGET) {
      u32 cutbin = (i > 0) ? (u32)(i - 1) : 0u;
      misc[24 + b] = cutbin << 19;
    }
  }
}

// ---------------- kernel 4: exact f64 keys for pass-peaks above cut ----------------
__global__ __launch_bounds__(256) void keygen_kernel(
    const float* __restrict__ in, const float* __restrict__ wc,
    const float* __restrict__ wsw, const float* __restrict__ convr,
    const u32* __restrict__ passlist, u32* __restrict__ misc, u64* __restrict__ keybuf)
{
  int gtid = blockIdx.x * 256 + threadIdx.x;
  int gsz = gridDim.x * 256;
  for (int b = 0; b < BATCH; ++b) {
    int np = (int)min(misc[b], (u32)CAPP);
    u32 cutb = misc[24 + b];
    for (int i = gtid; i < np; i += gsz) {
      int p = (int)passlist[(size_t)b * CAPP + i];
      float fv = convr[(size_t)b * HW + p];
      if (__float_as_uint(fv) < cutb) continue;
      double v = conv_resp_f64(in, wc, wsw, b, p >> 10, p & (W - 1));
      u32 pos = atomicAdd(&misc[16 + b], 1u);
      if (pos < KEYCAP) keybuf[(size_t)b * KEYCAP + pos] = make_key(v, p);
    }
  }
}

// ---------------- kernel 5: exact f64 recheck, one wave per uncertain pixel ----------------
__global__ __launch_bounds__(256) void recheck_kernel(
    const float* __restrict__ in, const float* __restrict__ wc,
    const float* __restrict__ wsw, const float* __restrict__ convr,
    const u32* __restrict__ checklist, u32* __restrict__ misc, u64* __restrict__ keybuf)
{
  int wid = (blockIdx.x * 256 + threadIdx.x) >> 6;
  int lane = threadIdx.x & 63;
  int nw = (gridDim.x * 256) >> 6;

  for (int b = 0; b < BATCH; ++b) {
    int nc = (int)min(misc[8 + b], (u32)CAPC);
    u32 cutb = misc[24 + b];
    for (int i = wid; i < nc; i += nw) {
      int p = (int)checklist[(size_t)b * CAPC + i];
      int y = p >> 10, x = p & (W - 1);

      double v = 0.0;
      if (lane < 25)
        v = conv_resp_f64(in, wc, wsw, b, y + lane / 5 - 2, x + lane % 5 - 2);

      double c[25];
      #pragma unroll
      for (int k = 0; k < 25; ++k) c[k] = __shfl(v, k);

      double cs0[5], cs1[5], cs2[5];
      #pragma unroll
      for (int j = 0; j < 5; ++j) {
        cs0[j] = c[0 + j] + c[5 + j] + c[10 + j];
        cs1[j] = c[5 + j] + c[10 + j] + c[15 + j];
        cs2[j] = c[10 + j] + c[15 + j] + c[20 + j];
      }
      double val = c[12];

      double sc = (cs1[1] + cs1[2] + cs1[3]) * (1.0 / 9.0);
      if (!(sc > 0.1)) continue;
      bool pk = true;
      #pragma unroll
      for (int j = 0; j < 3; ++j) {
        pk = pk && (sc >= (cs0[j] + cs0[j + 1] + cs0[j + 2]) * (1.0 / 9.0));
        pk = pk && (sc >= (cs2[j] + cs2[j + 1] + cs2[j + 2]) * (1.0 / 9.0));
      }
      pk = pk && (sc >= (cs1[0] + cs1[1] + cs1[2]) * (1.0 / 9.0));
      pk = pk && (sc >= (cs1[2] + cs1[3] + cs1[4]) * (1.0 / 9.0));
      if (!pk) continue;
      if (!(val > 0.1)) continue;

      float fv = convr[(size_t)b * HW + p];
      if (__float_as_uint(fv) < cutb) continue;

      if (lane == 0) {
        u32 pos = atomicAdd(&misc[16 + b], 1u);
        if (pos < KEYCAP) keybuf[(size_t)b * KEYCAP + pos] = make_key(val, p);
      }
    }
  }
}

// ---------------- kernel 6: per-batch bitonic sort of keyed set -> center_pred ----------
__global__ __launch_bounds__(1024) void sort_out_kernel(
    const u64* __restrict__ keybuf, const u32* __restrict__ misc,
    const float* __restrict__ convr, float* __restrict__ center)
{
  __shared__ u64 sk[KEYCAP];
  int b = blockIdx.x;
  int tid = threadIdx.x;
  int M = (int)min(misc[16 + b], (u32)KEYCAP);
  const u64* kb = keybuf + (size_t)b * KEYCAP;
  for (int i = tid; i < KEYCAP; i += 1024) sk[i] = (i < M) ? kb[i] : 0ULL;

  for (int k = 2; k <= KEYCAP; k <<= 1) {
    for (int j = k >> 1; j > 0; j >>= 1) {
      __syncthreads();
      for (int i = tid; i < KEYCAP; i += 1024) {
        int l = i ^ j;
        if (l > i) {
          u64 a = sk[i], bb = sk[l];
          bool up = ((i & k) == 0);
          bool sw = up ? (a < bb) : (a > bb);
          if (sw) { sk[i] = bb; sk[l] = a; }
        }
      }
    }
  }
  __syncthreads();

  for (int i = tid; i < KTOP; i += 1024) {
    float* o = center + ((size_t)b * KTOP + i) * 5;
    if (i < M) {
      u64 key = sk[i];
      u32 p = (~(u32)key) & 0xFFFFFu;
      float v = convr[(size_t)b * HW + p];
      o[0] = 1.0f;
      o[1] = (float)(p & (W - 1));
      o[2] = (float)(p >> 10);
      o[3] = v;
      o[4] = v;
    } else {
      o[0] = 0.f; o[1] = 0.f; o[2] = 0.f; o[3] = 0.f; o[4] = 0.f;
    }
  }
}

extern "C" void kernel_launch(void* const* d_in, const int* in_sizes, int n_in,
                              void* d_out, int out_size, void* d_ws, size_t ws_size,
                              hipStream_t stream) {
  const float* in  = (const float*)d_in[0];
  const float* wc  = (const float*)d_in[1];
  const float* wsw = (const float*)d_in[2];

  float* out0   = (float*)d_out;                     // (8,3,1024,1024)
  float* center = out0 + (size_t)BATCH * 3 * HW;     // (8,2048,5)
  float* convr  = center + (size_t)BATCH * KTOP * 5; // (8,1,1024,1024)

  char* w = (char*)d_ws;
  u32* misc      = (u32*)(w + OFF_MISC);
  u32* hist      = (u32*)(w + OFF_HIST);
  u32* passlist  = (u32*)(w + OFF_PASS);
  u32* checklist = (u32*)(w + OFF_CHK);
  u64* keybuf    = (u64*)(w + OFF_KEY);

  hipMemsetAsync(w, 0, OFF_PASS, stream);  // misc + hist

  conv32_kernel<<<NPIX / 4 / 256, 256, 0, stream>>>(in, wc, wsw, out0, convr);
  screen_kernel<<<NPIX / 4 / 256, 256, 0, stream>>>(convr, passlist, checklist, hist, misc);
  cutscan_kernel<<<BATCH, 1024, 0, stream>>>(hist, misc);
  keygen_kernel<<<2048, 256, 0, stream>>>(in, wc, wsw, convr, passlist, misc, keybuf);
  recheck_kernel<<<1024, 256, 0, stream>>>(in, wc, wsw, convr, checklist, misc, keybuf);
  sort_out_kernel<<<BATCH, 1024, 0, stream>>>(keybuf, misc, convr, center);
}

// Round 9
// 1818.306 us; speedup vs baseline: 1.7470x; 1.7470x over previous
//
#include <hip/hip_runtime.h>
#include <cstdint>

typedef unsigned int u32;
typedef unsigned long long u64;

#define BATCH 8
#define H 1024
#define W 1024
#define HW (H*W)
#define NPIX (BATCH*HW)
#define KTOP 2048
#define NBIN 8192
#define KEYCAP 8192
#define CAPP 131072
#define CAPC 65536
#define TARGET 2080

#define D9 1e-3f
#define DV 1e-4f

// fused tile geometry
#define TOX 64
#define TOY 16
#define CCX 72          // conv cols: tx0-4 .. tx0+67
#define CCY 20          // conv rows: ty0-2 .. ty0+17
#define CSTR 76         // f32 row stride (16B-aligned rows)

// ws layout (bytes); [0, OFF_PASS) memset to 0 each launch
#define OFF_MISC 0                          // u32: pass[0..8) chk[8..16) kcnt[16..24) cut[24..32)
#define OFF_HIST 4096                       // u32[8][NBIN] = 256 KB
#define OFF_PASS (OFF_HIST + BATCH*NBIN*4)
#define OFF_CHK  (OFF_PASS + BATCH*CAPP*4)
#define OFF_KEY  (OFF_CHK  + BATCH*CAPC*4)

#define LD4(p) (*reinterpret_cast<const float4*>(p))
#define ST4(p,v) (*reinterpret_cast<float4*>(p) = (v))

// ---------------- f64 dilated conv + relu (IDENTICAL to green rounds 3-8) ----------------
__device__ __forceinline__ double conv_resp_f64(
    const float* __restrict__ in, const float* __restrict__ wc,
    const float* __restrict__ wsw, int b, int y, int x)
{
  const float* base = in + (size_t)b * 3 * HW;
  const float* Sp = base;
  const float* Cp = base + HW;
  double resp = 0.0;
  const int dil[3] = {1, 4, 16};
  #pragma unroll
  for (int di = 0; di < 3; ++di) {
    int d = dil[di];
    double ac = 0.0, as = 0.0;
    #pragma unroll
    for (int ky = 0; ky < 3; ++ky) {
      int yy = y + (ky - 1) * d;
      bool yok = ((unsigned)yy < (unsigned)H);
      #pragma unroll
      for (int kx = 0; kx < 3; ++kx) {
        int xx = x + (kx - 1) * d;
        bool ok = yok && ((unsigned)xx < (unsigned)W);
        double a  = ok ? (double)Cp[yy * W + xx] : 0.0;
        double s2 = ok ? (double)Sp[yy * W + xx] : 0.0;
        ac = fma(a,  (double)wc[di * 9 + ky * 3 + kx], ac);
        as = fma(s2, (double)wsw[di * 9 + ky * 3 + kx], as);
      }
    }
    resp += ac;
    resp += as;
  }
  return resp > 0.0 ? resp : 0.0;
}

__device__ __forceinline__ u64 make_key(double val, int p) {
  u64 dbits = __double_as_longlong(val);
  return (dbits & ~0xFFFFFull) | (u64)((~(u32)p) & 0xFFFFFu);
}

// ---------------- guarded scalar f32 conv (border path, identical to round 8) -------------
__device__ __forceinline__ float conv_f32_guard(
    const float* __restrict__ Sp, const float* __restrict__ Cp,
    const float* __restrict__ wc, const float* __restrict__ wsw, int y, int x)
{
  float resp = 0.f;
  #pragma unroll
  for (int di = 0; di < 3; ++di) {
    const int d = (di == 0) ? 1 : (di == 1) ? 4 : 16;
    float ac = 0.f, as = 0.f;
    #pragma unroll
    for (int ky = 0; ky < 3; ++ky) {
      int yy = y + (ky - 1) * d;
      bool yok = ((unsigned)yy < (unsigned)H);
      #pragma unroll
      for (int kx = 0; kx < 3; ++kx) {
        int xx = x + (kx - 1) * d;
        bool ok = yok && ((unsigned)xx < (unsigned)W);
        float a  = ok ? Cp[yy * W + xx] : 0.f;
        float s2 = ok ? Sp[yy * W + xx] : 0.f;
        ac = fmaf(a,  wc[di * 9 + ky * 3 + kx], ac);
        as = fmaf(s2, wsw[di * 9 + ky * 3 + kx], as);
      }
    }
    resp += ac;
    resp += as;
  }
  return resp;
}

// ---------------- fused kernel: conv (f4) -> LDS -> outputs + in-LDS screen ----------------
__global__ __launch_bounds__(256) void conv_screen_kernel(
    const float* __restrict__ in, const float* __restrict__ wc,
    const float* __restrict__ wsw, float* __restrict__ out0,
    float* __restrict__ convr, u32* __restrict__ passlist,
    u32* __restrict__ checklist, u32* __restrict__ hist, u32* __restrict__ misc)
{
  __shared__ float sconv[CCY][CSTR];

  int b = blockIdx.z;
  int tx0 = blockIdx.x * TOX;
  int ty0 = blockIdx.y * TOY;
  const float* Sp = in + (size_t)b * 3 * HW;
  const float* Cp = Sp + HW;
  const float* Rp = Sp + 2 * HW;
  float* ob = out0 + (size_t)b * 3 * HW;
  float* cb = convr + (size_t)b * HW;

  // ---- elementwise outputs for the 64x16 tile (one f4 group per thread) ----
  {
    int ly = threadIdx.x >> 4;
    int lx4 = (threadIdx.x & 15) * 4;
    int p0 = (ty0 + ly) * W + tx0 + lx4;
    float4 S4 = LD4(Sp + p0);
    float4 C4 = LD4(Cp + p0);
    float4 R4 = LD4(Rp + p0);
    ST4(ob + p0, S4);
    ST4(ob + HW + p0, C4);
    float4 E4 = make_float4(expf(R4.x) - 1.f, expf(R4.y) - 1.f,
                            expf(R4.z) - 1.f, expf(R4.w) - 1.f);
    ST4(ob + 2 * HW + p0, E4);
  }

  // ---- f32 conv over 72x20 region -> LDS (+ global convr for the 64x16 core) ----
  for (int g = threadIdx.x; g < (CCX / 4) * CCY; g += 256) {
    int gr = g / (CCX / 4);
    int gc = g - gr * (CCX / 4);
    int gy = ty0 - 2 + gr;
    int gx0 = tx0 - 4 + gc * 4;
    float acc[4] = {0.f, 0.f, 0.f, 0.f};
    bool inimg_y = ((unsigned)gy < (unsigned)H);
    bool interior = inimg_y && gy >= 16 && gy <= H - 17 && gx0 >= 16 && gx0 <= W - 20;
    if (interior) {
      #define DIL_CONTIG(PTR, WP, DI, D) { \
        _Pragma("unroll") \
        for (int ky = 0; ky < 3; ++ky) { \
          const float* rp = (PTR) + (gy + (ky - 1) * (D)) * W; \
          float4 Lq = LD4(rp + gx0 - 4); \
          float4 Mq = LD4(rp + gx0); \
          float4 Rq = LD4(rp + gx0 + 4); \
          float win[12] = {Lq.x,Lq.y,Lq.z,Lq.w, Mq.x,Mq.y,Mq.z,Mq.w, Rq.x,Rq.y,Rq.z,Rq.w}; \
          _Pragma("unroll") \
          for (int kx = 0; kx < 3; ++kx) { \
            float wv = (WP)[(DI) * 9 + ky * 3 + kx]; \
            _Pragma("unroll") \
            for (int i = 0; i < 4; ++i) \
              acc[i] = fmaf(win[i + (kx - 1) * (D) + 4], wv, acc[i]); \
          } \
        } }
      #define DIL16F(PTR, WP, DI) { \
        _Pragma("unroll") \
        for (int ky = 0; ky < 3; ++ky) { \
          const float* rp = (PTR) + (gy + (ky - 1) * 16) * W; \
          float4 Lq = LD4(rp + gx0 - 16); \
          float4 Mq = LD4(rp + gx0); \
          float4 Rq = LD4(rp + gx0 + 16); \
          float win[12] = {Lq.x,Lq.y,Lq.z,Lq.w, Mq.x,Mq.y,Mq.z,Mq.w, Rq.x,Rq.y,Rq.z,Rq.w}; \
          _Pragma("unroll") \
          for (int kx = 0; kx < 3; ++kx) { \
            float wv = (WP)[(DI) * 9 + ky * 3 + kx]; \
            _Pragma("unroll") \
            for (int i = 0; i < 4; ++i) \
              acc[i] = fmaf(win[kx * 4 + i], wv, acc[i]); \
          } \
        } }
      DIL_CONTIG(Cp, wc, 0, 1)
      DIL_CONTIG(Sp, wsw, 0, 1)
      DIL_CONTIG(Cp, wc, 1, 4)
      DIL_CONTIG(Sp, wsw, 1, 4)
      DIL16F(Cp, wc, 2)
      DIL16F(Sp, wsw, 2)
    } else {
      #pragma unroll
      for (int i = 0; i < 4; ++i) {
        int gx = gx0 + i;
        acc[i] = (inimg_y && (unsigned)gx < (unsigned)W)
                   ? conv_f32_guard(Sp, Cp, wc, wsw, gy, gx) : 0.f;
      }
    }
    float4 cv = make_float4(fmaxf(acc[0], 0.f), fmaxf(acc[1], 0.f),
                            fmaxf(acc[2], 0.f), fmaxf(acc[3], 0.f));
    *reinterpret_cast<float4*>(&sconv[gr][gc * 4]) = cv;
    if (gr >= 2 && gr <= CCY - 3 && gc >= 1 && gc <= CCX / 4 - 2)
      ST4(cb + gy * W + gx0, cv);
  }
  __syncthreads();

  // ---- in-LDS screen of the 64x16 tile, wave-aggregated appends ----
  int lane = threadIdx.x & 63;
  for (int r = 0; r < (TOX * TOY) / 256; ++r) {
    int idx = r * 256 + threadIdx.x;
    int ly = idx >> 6;
    int lx = idx & 63;
    int x = tx0 + lx, y = ty0 + ly;
    bool act = (y >= 5 && y <= H - 6 && x >= 5 && x <= W - 6);

    bool cand = false, pass = false;
    float val = 0.f;
    if (act) {
      float vs0[5], vs1[5], vs2[5];
      #pragma unroll
      for (int j = 0; j < 5; ++j) {
        int c = lx + 2 + j;
        float a0 = sconv[ly + 0][c];
        float a1 = sconv[ly + 1][c];
        float a2 = sconv[ly + 2][c];
        float a3 = sconv[ly + 3][c];
        float a4 = sconv[ly + 4][c];
        vs0[j] = a0 + a1 + a2;
        vs1[j] = a1 + a2 + a3;
        vs2[j] = a2 + a3 + a4;
      }
      float hs0[3], hs1[3], hs2[3];
      #pragma unroll
      for (int j = 0; j < 3; ++j) {
        hs0[j] = vs0[j] + vs0[j + 1] + vs0[j + 2];
        hs1[j] = vs1[j] + vs1[j + 1] + vs1[j + 2];
        hs2[j] = vs2[j] + vs2[j + 1] + vs2[j + 2];
      }
      float sc9 = hs1[1];
      val = sconv[ly + 2][lx + 4];
      float m9 = fmaxf(fmaxf(fmaxf(hs0[0], hs0[1]), fmaxf(hs0[2], hs1[0])),
                       fmaxf(fmaxf(hs1[2], hs2[0]), fmaxf(hs2[1], hs2[2])));
      cand = !((sc9 < 0.9f - D9) || (sc9 < m9 - D9) || (val < 0.1f - DV));
      pass = cand && (sc9 > 0.9f + D9) && (sc9 >= m9 + D9) && (val > 0.1f + DV);
    }

    u64 pm = __ballot(pass);
    if (pass) {
      int leader = __ffsll((unsigned long long)pm) - 1;
      u32 base = 0;
      if (lane == leader) base = atomicAdd(&misc[b], (u32)__popcll(pm));
      base = __shfl(base, leader);
      u32 rk = (u32)__popcll(pm & ((1ull << lane) - 1ull));
      if (base + rk < CAPP) passlist[(size_t)b * CAPP + base + rk] = (u32)(y * W + x);
      atomicAdd(&hist[b * NBIN + (__float_as_uint(val) >> 19)], 1u);
    }
    bool chk = cand && !pass;
    u64 cm = __ballot(chk);
    if (chk) {
      int leader = __ffsll((unsigned long long)cm) - 1;
      u32 base = 0;
      if (lane == leader) base = atomicAdd(&misc[8 + b], (u32)__popcll(cm));
      base = __shfl(base, leader);
      u32 rk = (u32)__popcll(cm & ((1ull << lane) - 1ull));
      if (base + rk < CAPC) checklist[(size_t)b * CAPC + base + rk] = (u32)(y * W + x);
    }
  }
}

// ---------------- suffix-scan hist -> f32 cut (rank TARGET, one-bin slack) ------
__global__ __launch_bounds__(1024) void cutscan_kernel(
    const u32* __restrict__ hist, u32* __restrict__ misc)
{
  __shared__ u32 sfx[NBIN];
  int b = blockIdx.x;
  int tid = threadIdx.x;
  const u32* h = hist + b * NBIN;
  #pragma unroll
  for (int k = 0; k < 8; ++k) sfx[tid * 8 + k] = h[tid * 8 + k];
  __syncthreads();

  for (int off = 1; off < NBIN; off <<= 1) {
    u32 t[8];
    #pragma unroll
    for (int k = 0; k < 8; ++k) {
      int i = tid * 8 + k;
      t[k] = (i + off < NBIN) ? sfx[i + off] : 0u;
    }
    __syncthreads();
    #pragma unroll
    for (int k = 0; k < 8; ++k) sfx[tid * 8 + k] += t[k];
    __syncthreads();
  }

  if (sfx[0] < TARGET) return;

  #pragma unroll
  for (int k = 0; k < 8; ++k) {
    int i = tid * 8 + k;
    u32 s = sfx[i];
    u32 nxt = (i + 1 < NBIN) ? sfx[i + 1] : 0u;
    if (s >= TARGET && nxt < TARGET) {
      u32 cutbin = (i > 0) ? (u32)(i - 1) : 0u;
      misc[24 + b] = cutbin << 19;
    }
  }
}

// ---------------- exact f64 keys for pass-peaks above cut ----------------
__global__ __launch_bounds__(256) void keygen_kernel(
    const float* __restrict__ in, const float* __restrict__ wc,
    const float* __restrict__ wsw, const float* __restrict__ convr,
    const u32* __restrict__ passlist, u32* __restrict__ misc, u64* __restrict__ keybuf)
{
  int gtid = blockIdx.x * 256 + threadIdx.x;
  int gsz = gridDim.x * 256;
  for (int b = 0; b < BATCH; ++b) {
    int np = (int)min(misc[b], (u32)CAPP);
    u32 cutb = misc[24 + b];
    for (int i = gtid; i < np; i += gsz) {
      int p = (int)passlist[(size_t)b * CAPP + i];
      float fv = convr[(size_t)b * HW + p];
      if (__float_as_uint(fv) < cutb) continue;
      double v = conv_resp_f64(in, wc, wsw, b, p >> 10, p & (W - 1));
      u32 pos = atomicAdd(&misc[16 + b], 1u);
      if (pos < KEYCAP) keybuf[(size_t)b * KEYCAP + pos] = make_key(v, p);
    }
  }
}

// ---------------- exact f64 recheck, one wave per uncertain pixel ----------------
__global__ __launch_bounds__(256) void recheck_kernel(
    const float* __restrict__ in, const float* __restrict__ wc,
    const float* __restrict__ wsw, const float* __restrict__ convr,
    const u32* __restrict__ checklist, u32* __restrict__ misc, u64* __restrict__ keybuf)
{
  int wid = (blockIdx.x * 256 + threadIdx.x) >> 6;
  int lane = threadIdx.x & 63;
  int nw = (gridDim.x * 256) >> 6;

  for (int b = 0; b < BATCH; ++b) {
    int nc = (int)min(misc[8 + b], (u32)CAPC);
    u32 cutb = misc[24 + b];
    for (int i = wid; i < nc; i += nw) {
      int p = (int)checklist[(size_t)b * CAPC + i];
      int y = p >> 10, x = p & (W - 1);

      double v = 0.0;
      if (lane < 25)
        v = conv_resp_f64(in, wc, wsw, b, y + lane / 5 - 2, x + lane % 5 - 2);

      double c[25];
      #pragma unroll
      for (int k = 0; k < 25; ++k) c[k] = __shfl(v, k);

      double cs0[5], cs1[5], cs2[5];
      #pragma unroll
      for (int j = 0; j < 5; ++j) {
        cs0[j] = c[0 + j] + c[5 + j] + c[10 + j];
        cs1[j] = c[5 + j] + c[10 + j] + c[15 + j];
        cs2[j] = c[10 + j] + c[15 + j] + c[20 + j];
      }
      double val = c[12];

      double sc = (cs1[1] + cs1[2] + cs1[3]) * (1.0 / 9.0);
      if (!(sc > 0.1)) continue;
      bool pk = true;
      #pragma unroll
      for (int j = 0; j < 3; ++j) {
        pk = pk && (sc >= (cs0[j] + cs0[j + 1] + cs0[j + 2]) * (1.0 / 9.0));
        pk = pk && (sc >= (cs2[j] + cs2[j + 1] + cs2[j + 2]) * (1.0 / 9.0));
      }
      pk = pk && (sc >= (cs1[0] + cs1[1] + cs1[2]) * (1.0 / 9.0));
      pk = pk && (sc >= (cs1[2] + cs1[3] + cs1[4]) * (1.0 / 9.0));
      if (!pk) continue;
      if (!(val > 0.1)) continue;

      float fv = convr[(size_t)b * HW + p];
      if (__float_as_uint(fv) < cutb) continue;

      if (lane == 0) {
        u32 pos = atomicAdd(&misc[16 + b], 1u);
        if (pos < KEYCAP) keybuf[(size_t)b * KEYCAP + pos] = make_key(val, p);
      }
    }
  }
}

// ---------------- per-batch bitonic sort of keyed set -> center_pred ----------
__global__ __launch_bounds__(1024) void sort_out_kernel(
    const u64* __restrict__ keybuf, const u32* __restrict__ misc,
    const float* __restrict__ convr, float* __restrict__ center)
{
  __shared__ u64 sk[KEYCAP];
  int b = blockIdx.x;
  int tid = threadIdx.x;
  int M = (int)min(misc[16 + b], (u32)KEYCAP);
  const u64* kb = keybuf + (size_t)b * KEYCAP;
  for (int i = tid; i < KEYCAP; i += 1024) sk[i] = (i < M) ? kb[i] : 0ULL;

  for (int k = 2; k <= KEYCAP; k <<= 1) {
    for (int j = k >> 1; j > 0; j >>= 1) {
      __syncthreads();
      for (int i = tid; i < KEYCAP; i += 1024) {
        int l = i ^ j;
        if (l > i) {
          u64 a = sk[i], bb = sk[l];
          bool up = ((i & k) == 0);
          bool sw = up ? (a < bb) : (a > bb);
          if (sw) { sk[i] = bb; sk[l] = a; }
        }
      }
    }
  }
  __syncthreads();

  for (int i = tid; i < KTOP; i += 1024) {
    float* o = center + ((size_t)b * KTOP + i) * 5;
    if (i < M) {
      u64 key = sk[i];
      u32 p = (~(u32)key) & 0xFFFFFu;
      float v = convr[(size_t)b * HW + p];
      o[0] = 1.0f;
      o[1] = (float)(p & (W - 1));
      o[2] = (float)(p >> 10);
      o[3] = v;
      o[4] = v;
    } else {
      o[0] = 0.f; o[1] = 0.f; o[2] = 0.f; o[3] = 0.f; o[4] = 0.f;
    }
  }
}

extern "C" void kernel_launch(void* const* d_in, const int* in_sizes, int n_in,
                              void* d_out, int out_size, void* d_ws, size_t ws_size,
                              hipStream_t stream) {
  const float* in  = (const float*)d_in[0];
  const float* wc  = (const float*)d_in[1];
  const float* wsw = (const float*)d_in[2];

  float* out0   = (float*)d_out;                     // (8,3,1024,1024)
  float* center = out0 + (size_t)BATCH * 3 * HW;     // (8,2048,5)
  float* convr  = center + (size_t)BATCH * KTOP * 5; // (8,1,1024,1024)

  char* w = (char*)d_ws;
  u32* misc      = (u32*)(w + OFF_MISC);
  u32* hist      = (u32*)(w + OFF_HIST);
  u32* passlist  = (u32*)(w + OFF_PASS);
  u32* checklist = (u32*)(w + OFF_CHK);
  u64* keybuf    = (u64*)(w + OFF_KEY);

  hipMemsetAsync(w, 0, OFF_PASS, stream);  // misc + hist

  conv_screen_kernel<<<dim3(W / TOX, H / TOY, BATCH), 256, 0, stream>>>(
      in, wc, wsw, out0, convr, passlist, checklist, hist, misc);
  cutscan_kernel<<<BATCH, 1024, 0, stream>>>(hist, misc);
  keygen_kernel<<<2048, 256, 0, stream>>>(in, wc, wsw, convr, passlist, misc, keybuf);
  recheck_kernel<<<1024, 256, 0, stream>>>(in, wc, wsw, convr, checklist, misc, keybuf);
  sort_out_kernel<<<BATCH, 1024, 0, stream>>>(keybuf, misc, convr, center);
}